// Round 1
// 338.510 us; speedup vs baseline: 1.1681x; 1.1681x over previous
//
#include <hip/hip_runtime.h>

typedef unsigned short u16;
typedef unsigned int u32;
typedef __bf16 bf16x8 __attribute__((ext_vector_type(8)));
typedef float f32x4 __attribute__((ext_vector_type(4)));
typedef u16 u16x8 __attribute__((ext_vector_type(8)));

__device__ __forceinline__ u16 f2bf(float f) {
    union { float f; u32 i; } v; v.f = f;
    u32 x = v.i;
    u32 r = (x + 0x7fffu + ((x >> 16) & 1u)) >> 16;
    return (u16)r;
}
__device__ __forceinline__ float bf2f(u16 u) {
    union { u32 i; float f; } v; v.i = ((u32)u) << 16; return v.f;
}

// async global->LDS, 16B per lane. LDS dest must be lane-linear per wave.
__device__ __forceinline__ void gld16(const void* g, void* l) {
    __builtin_amdgcn_global_load_lds(
        (const __attribute__((address_space(1))) void*)g,
        (__attribute__((address_space(3))) void*)l, 16, 0, 0);
}

// -------- weight transpose+convert: 4 matrices [512][512] fp32 -> bf16^T ---
__global__ __launch_bounds__(256) void transpose4(
    const float* __restrict__ s0, const float* __restrict__ s1,
    const float* __restrict__ s2, const float* __restrict__ s3,
    u16* __restrict__ d0, u16* __restrict__ d1,
    u16* __restrict__ d2, u16* __restrict__ d3)
{
    int bx = blockIdx.x;
    int mat = bx >> 8;          // 0..3
    int tile = bx & 255;        // 16x16 tiles of 32x32
    int tx = (tile & 15) * 32;
    int ty = (tile >> 4) * 32;
    const float* src = (mat == 0) ? s0 : (mat == 1) ? s1 : (mat == 2) ? s2 : s3;
    u16* dst = (mat == 0) ? d0 : (mat == 1) ? d1 : (mat == 2) ? d2 : d3;

    __shared__ u16 tl[32][33];
    int col = threadIdx.x & 31;
    int r8  = threadIdx.x >> 5;   // 0..7
    #pragma unroll
    for (int k = 0; k < 4; ++k) {
        int rr = r8 + k * 8;
        tl[rr][col] = f2bf(src[(ty + rr) * 512 + tx + col]);
    }
    __syncthreads();
    #pragma unroll
    for (int k = 0; k < 4; ++k) {
        int rr = r8 + k * 8;
        dst[(tx + rr) * 512 + ty + col] = tl[col][rr];
    }
}

// -------- LayerNorm over H=512: fp32 in -> bf16 out, one wave per row -----
__global__ __launch_bounds__(256) void ln_k(
    const float* __restrict__ x, const float* __restrict__ g,
    const float* __restrict__ b, u16* __restrict__ y, int rows)
{
    int gid = blockIdx.x * blockDim.x + threadIdx.x;
    int row = gid >> 6;
    int lane = gid & 63;
    if (row >= rows) return;

    const float* xr = x + (size_t)row * 512 + lane * 8;
    float4 a0 = *(const float4*)xr;
    float4 a1 = *(const float4*)(xr + 4);
    float f[8] = {a0.x, a0.y, a0.z, a0.w, a1.x, a1.y, a1.z, a1.w};
    float s = 0.f, s2 = 0.f;
    #pragma unroll
    for (int e = 0; e < 8; ++e) { s += f[e]; s2 += f[e] * f[e]; }
    #pragma unroll
    for (int o = 32; o > 0; o >>= 1) { s += __shfl_xor(s, o); s2 += __shfl_xor(s2, o); }
    const float inv = 1.0f / 512.0f;
    float mean = s * inv;
    float var  = s2 * inv - mean * mean;
    float rstd = rsqrtf(var + 1e-5f);

    float4 g0 = *(const float4*)(g + lane * 8);
    float4 g1 = *(const float4*)(g + lane * 8 + 4);
    float4 b0 = *(const float4*)(b + lane * 8);
    float4 b1 = *(const float4*)(b + lane * 8 + 4);
    float gg[8] = {g0.x, g0.y, g0.z, g0.w, g1.x, g1.y, g1.z, g1.w};
    float bb[8] = {b0.x, b0.y, b0.z, b0.w, b1.x, b1.y, b1.z, b1.w};
    u16x8 ov;
    #pragma unroll
    for (int e = 0; e < 8; ++e)
        ov[e] = f2bf((f[e] - mean) * rstd * gg[e] + bb[e]);
    *(u16x8*)(y + (size_t)row * 512 + lane * 8) = ov;
}

// -------- GEMM: C[M,N] = A[M,K](bf16) @ Bt[N,K](bf16)^T, 128x128 tile -----
// Staging via global_load_lds (width 16). Bank-conflict fix per rule #21:
// LDS stays linear; the *global source* granule is XOR-permuted with
// (row>>1)&3 and the same XOR is applied on the ds_read side.
// MODE 0: dual-B -> out0 = A@B0 + bias0 (bf16), out1 = A@B1 + bias1 (bf16)
// MODE 1: out0 = relu(A@B0 + bias0) (bf16)
// MODE 2: out0 = A@B0 + bias0 + resid (fp32 out; resid fp32, same-thread alias-safe)
template <int MODE>
__global__ __launch_bounds__(256, 2) void gemm_bt(
    const u16* __restrict__ A, const u16* __restrict__ Bt0,
    const u16* __restrict__ Bt1, const float* __restrict__ bias0,
    const float* __restrict__ bias1, const float* __restrict__ resid,
    void* __restrict__ out0v, u16* __restrict__ out1)
{
    constexpr int Kd = 512, Nd = 512;
    __shared__ __align__(16) u16 As[128 * 32];
    __shared__ __align__(16) u16 Bs0[128 * 32];
    __shared__ __align__(16) u16 Bs1[(MODE == 0) ? 128 * 32 : 8];

    // XCD-contiguous tile remap (1024 % 8 == 0 -> bijective):
    // XCD k gets a contiguous run of 128 tiles = 32 m-tiles * 4 n-tiles,
    // so A-panels stay in that XCD's L2.
    int bx = blockIdx.x;
    bx = (bx & 7) * 128 + (bx >> 3);
    int m0 = (bx >> 2) * 128;
    int n0 = (bx & 3) * 128;
    int tid = threadIdx.x;
    int lane = tid & 63;
    int w = tid >> 6;
    int wm = w & 1, wn = w >> 1;
    int l16 = lane & 15;
    int quad = lane >> 4;

    f32x4 acc0[4][4] = {};
    f32x4 acc1[4][4] = {};

    // staging: chunk ch covers LDS granule ch (16B); it must carry global
    // granule g ^ ((row>>1)&3) of row = ch>>2.
    int ch0 = tid, ch1 = tid + 256;
    int row0 = ch0 >> 2, row1 = ch1 >> 2;
    int g0 = (ch0 & 3) ^ ((ch0 >> 3) & 3);
    int g1 = (ch1 & 3) ^ ((ch1 >> 3) & 3);
    const u16* a0p  = A   + (size_t)(m0 + row0) * Kd + g0 * 8;
    const u16* a1p  = A   + (size_t)(m0 + row1) * Kd + g1 * 8;
    const u16* b00p = Bt0 + (size_t)(n0 + row0) * Kd + g0 * 8;
    const u16* b01p = Bt0 + (size_t)(n0 + row1) * Kd + g1 * 8;
    const u16* b10p = (MODE == 0) ? Bt1 + (size_t)(n0 + row0) * Kd + g0 * 8 : nullptr;
    const u16* b11p = (MODE == 0) ? Bt1 + (size_t)(n0 + row1) * Kd + g1 * 8 : nullptr;

    for (int kt = 0; kt < Kd / 32; ++kt) {
        int k0 = kt * 32;
        gld16(a0p  + k0, &As [ch0 * 8]);
        gld16(a1p  + k0, &As [ch1 * 8]);
        gld16(b00p + k0, &Bs0[ch0 * 8]);
        gld16(b01p + k0, &Bs0[ch1 * 8]);
        if (MODE == 0) {
            gld16(b10p + k0, &Bs1[ch0 * 8]);
            gld16(b11p + k0, &Bs1[ch1 * 8]);
        }
        __syncthreads();

        bf16x8 af[4], bf0[4], bf1[4];
        #pragma unroll
        for (int i = 0; i < 4; ++i) {
            int ra = wm * 64 + i * 16 + l16;
            int rb = wn * 64 + i * 16 + l16;
            int ga = quad ^ ((ra >> 1) & 3);
            int gb = quad ^ ((rb >> 1) & 3);
            af[i]  = *(const bf16x8*)&As [ra * 32 + ga * 8];
            bf0[i] = *(const bf16x8*)&Bs0[rb * 32 + gb * 8];
            if (MODE == 0)
                bf1[i] = *(const bf16x8*)&Bs1[rb * 32 + gb * 8];
        }
        #pragma unroll
        for (int i = 0; i < 4; ++i)
            #pragma unroll
            for (int j = 0; j < 4; ++j) {
                acc0[i][j] = __builtin_amdgcn_mfma_f32_16x16x32_bf16(af[i], bf0[j], acc0[i][j], 0, 0, 0);
                if (MODE == 0)
                    acc1[i][j] = __builtin_amdgcn_mfma_f32_16x16x32_bf16(af[i], bf1[j], acc1[i][j], 0, 0, 0);
            }
        __syncthreads();
    }

    #pragma unroll
    for (int j = 0; j < 4; ++j) {
        int col = n0 + wn * 64 + j * 16 + l16;
        float b0 = bias0[col];
        float b1v = (MODE == 0) ? bias1[col] : 0.f;
        #pragma unroll
        for (int i = 0; i < 4; ++i) {
            #pragma unroll
            for (int r = 0; r < 4; ++r) {
                int row = m0 + wm * 64 + i * 16 + quad * 4 + r;
                size_t off = (size_t)row * Nd + col;
                float v0 = acc0[i][j][r] + b0;
                if (MODE == 0) {
                    ((u16*)out0v)[off] = f2bf(v0);
                    out1[off] = f2bf(acc1[i][j][r] + b1v);
                } else if (MODE == 1) {
                    ((u16*)out0v)[off] = f2bf(fmaxf(v0, 0.f));
                } else {
                    ((float*)out0v)[off] = v0 + resid[off];
                }
            }
        }
    }
}

// -------- minGRU scan (chunked linear recurrence) --------------------------
// h_t = c_t*h_{t-1} + v_t ; c = sigmoid(-k), v = sigmoid(k)*g(hp), h_0 = 0.5
// Chunk length 32 (256 chunks/seq) -> 8192 waves at scanA/scanC = full
// occupancy. Chunk-state scan is 3-level: compose-16 / scan-16 / replay-16.
__device__ __forceinline__ void gate_cv(u16 kraw, u16 hraw, float& c, float& v) {
    float kk = bf2f(kraw);
    float hh = bf2f(hraw);
    float z = 1.f / (1.f + __expf(-kk));   // sigmoid(k)
    c = 1.f / (1.f + __expf(kk));          // sigmoid(-k)
    float gg = (hh >= 0.f) ? (hh + 0.5f) : 1.f / (1.f + __expf(-hh));
    v = z * gg;
}

// Pass A: per-chunk (C, V) composition over chunk length 32.
__global__ __launch_bounds__(256) void scanA(
    const u16* __restrict__ kb, const u16* __restrict__ hp,
    float* __restrict__ chC, float* __restrict__ chV)
{
    int gid = blockIdx.x * 256 + threadIdx.x;   // 524288 threads
    int h = gid & 511;
    int rest = gid >> 9;
    int b = rest & 3;
    int ch = rest >> 2;             // 0..255
    size_t base = ((size_t)(b * 8192 + ch * 32)) * 512 + h;
    float C = 1.f, V = 0.f;
    #pragma unroll 8
    for (int t = 0; t < 32; ++t) {
        float c, v;
        gate_cv(kb[base + (size_t)t * 512], hp[base + (size_t)t * 512], c, v);
        C *= c;
        V = fmaf(c, V, v);
    }
    int s = b * 512 + h;
    chC[ch * 2048 + s] = C;
    chV[ch * 2048 + s] = V;
}

// Pass B1: compose 16 chunks -> superchunk state (16 superchunks/seq).
__global__ __launch_bounds__(256) void scanB1(
    const float* __restrict__ chC, const float* __restrict__ chV,
    float* __restrict__ scC, float* __restrict__ scV)
{
    int gid = blockIdx.x * 256 + threadIdx.x;  // 32768 threads
    int s = gid & 2047;
    int sc = gid >> 11;    // 0..15
    float C = 1.f, V = 0.f;
    #pragma unroll 4
    for (int i = 0; i < 16; ++i) {
        int ch = sc * 16 + i;
        float c = chC[ch * 2048 + s];
        float v = chV[ch * 2048 + s];
        C *= c;
        V = fmaf(c, V, v);
    }
    scC[sc * 2048 + s] = C;
    scV[sc * 2048 + s] = V;
}

// Pass B2: serial scan over 16 superchunk states; write start h per sc.
__global__ __launch_bounds__(256) void scanB2(
    const float* __restrict__ scC, const float* __restrict__ scV,
    float* __restrict__ sst)
{
    int s = blockIdx.x * 256 + threadIdx.x;   // 0..2047
    float hcur = 0.5f;
    #pragma unroll
    for (int sc = 0; sc < 16; ++sc) {
        sst[sc * 2048 + s] = hcur;
        hcur = fmaf(scC[sc * 2048 + s], hcur, scV[sc * 2048 + s]);
    }
}

// Pass B3: replay 16 chunks inside each superchunk; write start h per chunk.
__global__ __launch_bounds__(256) void scanB3(
    const float* __restrict__ chC, const float* __restrict__ chV,
    const float* __restrict__ sst, float* __restrict__ hst)
{
    int gid = blockIdx.x * 256 + threadIdx.x;  // 32768 threads
    int s = gid & 2047;
    int sc = gid >> 11;
    float hcur = sst[sc * 2048 + s];
    #pragma unroll 4
    for (int i = 0; i < 16; ++i) {
        int ch = sc * 16 + i;
        hst[ch * 2048 + s] = hcur;
        hcur = fmaf(chC[ch * 2048 + s], hcur, chV[ch * 2048 + s]);
    }
}

// Pass C: replay chunk with known h_start; x2 = x + h (fp32 in, fp32 out).
__global__ __launch_bounds__(256) void scanC(
    const u16* __restrict__ kb, const u16* __restrict__ hp,
    const float* __restrict__ hst, const float* __restrict__ x,
    float* __restrict__ x2)
{
    int gid = blockIdx.x * 256 + threadIdx.x;   // 524288 threads
    int h = gid & 511;
    int rest = gid >> 9;
    int b = rest & 3;
    int ch = rest >> 2;
    size_t base = ((size_t)(b * 8192 + ch * 32)) * 512 + h;
    float hcur = hst[ch * 2048 + b * 512 + h];
    #pragma unroll 8
    for (int t = 0; t < 32; ++t) {
        float c, v;
        size_t off = base + (size_t)t * 512;
        gate_cv(kb[off], hp[off], c, v);
        hcur = fmaf(c, hcur, v);
        x2[off] = x[off] + hcur;
    }
}

// ---------------------------------------------------------------------------
// All I/O fp32 (per reference). Internals bf16 for MFMA.
// ws layout (total 99.5 MiB, unchanged footprint):
//   wt  @ 0      : 2 MiB   (4 transposed bf16 weights)
//   a   @ 3.5 MiB: 32 MiB  bf16 (LN1 out -> LN2 out)
//     scan temps alias a's region (a is dead between gemm0 and LN2):
//     chC @ 3.5M (2M) ; chV @ 5.5M (2M) ; hst @ 7.5M (2M)
//     scC @ 9.5M (128K) ; scV ; sst
//   kb  @ 35.5 M : 32 MiB  bf16 (k preact -> FFN hidden)
//   hp  @ 67.5 M : 32 MiB  bf16 (h~ preact)
// d_out (fp32, 64 MiB) holds x2 after scanC, then the final output
// (gemm2 reads resid[off] then writes out[off] from the same thread).
extern "C" void kernel_launch(void* const* d_in, const int* in_sizes, int n_in,
                              void* d_out, int out_size, void* d_ws, size_t ws_size,
                              hipStream_t stream)
{
    const float* x    = (const float*)d_in[0];
    const float* ln1g = (const float*)d_in[1];
    const float* ln1b = (const float*)d_in[2];
    const float* Wz   = (const float*)d_in[3];
    const float* bz   = (const float*)d_in[4];
    const float* Wh   = (const float*)d_in[5];
    const float* bh   = (const float*)d_in[6];
    const float* ln2g = (const float*)d_in[7];
    const float* ln2b = (const float*)d_in[8];
    const float* W1   = (const float*)d_in[9];
    const float* b1   = (const float*)d_in[10];
    const float* W2   = (const float*)d_in[11];
    const float* b2   = (const float*)d_in[12];
    float* out = (float*)d_out;

    char* ws = (char*)d_ws;
    constexpr size_t MB = 1024 * 1024;
    u16* Wzt = (u16*)(ws);
    u16* Wht = Wzt + 262144;
    u16* W1t = Wzt + 524288;
    u16* W2t = Wzt + 786432;
    u16* a  = (u16*)(ws + 3 * MB + 512 * 1024);
    u16* kb = (u16*)(ws + 35 * MB + 512 * 1024);
    u16* hp = (u16*)(ws + 67 * MB + 512 * 1024);
    // scan temps alias 'a' (dead in that interval)
    float* chC = (float*)(ws + 3 * MB + 512 * 1024);
    float* chV = chC + 524288;          // +2 MiB
    float* hst = chV + 524288;          // +2 MiB
    float* scC = hst + 524288;          // +2 MiB
    float* scV = scC + 32768;           // +128 KiB
    float* sst = scV + 32768;           // +128 KiB

    transpose4<<<1024, 256, 0, stream>>>(Wz, Wh, W1, W2, Wzt, Wht, W1t, W2t);
    // a = bf16(LN1(x))
    ln_k<<<8192, 256, 0, stream>>>(x, ln1g, ln1b, a, 32768);
    // kb = k preact (bf16), hp = h~ preact (bf16)
    gemm_bt<0><<<1024, 256, 0, stream>>>(a, Wzt, Wht, bz, bh, nullptr, kb, hp);
    scanA<<<2048, 256, 0, stream>>>(kb, hp, chC, chV);
    scanB1<<<128, 256, 0, stream>>>(chC, chV, scC, scV);
    scanB2<<<8, 256, 0, stream>>>(scC, scV, sst);
    scanB3<<<128, 256, 0, stream>>>(chC, chV, sst, hst);
    // d_out = x + h  (fp32 residual stream)
    scanC<<<2048, 256, 0, stream>>>(kb, hp, hst, x, out);
    // a = bf16(LN2(d_out))
    ln_k<<<8192, 256, 0, stream>>>(out, ln2g, ln2b, a, 32768);
    // kb = relu(a @ W1 + b1)  (bf16 hidden)
    gemm_bt<1><<<1024, 256, 0, stream>>>(a, W1t, nullptr, b1, nullptr, nullptr, kb, nullptr);
    // d_out = kb @ W2 + b2 + d_out  (fp32)
    gemm_bt<2><<<1024, 256, 0, stream>>>(kb, W2t, nullptr, b2, nullptr, out, out, nullptr);
}